// Round 5
// baseline (158.057 us; speedup 1.0000x reference)
//
#include <hip/hip_runtime.h>
#include <math.h>

// Problem constants (from reference setup_inputs)
#define B_     8
#define H_     32
#define D_     128
#define SMAX_  4096
#define HD_    (H_ * D_)     // 4096 floats = 16 KB per position
#define SCALE  0.5f
#define PSPLIT 128           // position splits (strided map)
#define NHG    4             // head groups of 8 heads -> 4 KB per position per block
#define PSTRIDE 132          // record: acc[128], m, l, pad2  (16B-aligned acc)

// ---------------------------------------------------------------------------
// Kernel 1: flash-decode partials, fine-grained work units.
// grid = NHG * PSPLIT * B = 4096 blocks, 256 threads, ~40 VGPR ->
// 8 blocks/CU resident; remaining blocks dispatch dynamically as CUs drain
// (hardware load balancing). Block (hg, split, b):
//   thread t: head h = hg*8 + (t>>5), dims (t&31)*4 .. +3  -> the block reads
//   k[b,p,hg*8:(hg+1)*8,:] = 4 KB contiguous per position (offset t*16 B).
// STRIDED split->position map: split s handles p = s, s+128, ... p < sl,
// plus the appended token (knew/vnew) iff sl % 128 == s -> every split gets
// ceil(total/128) +-1 positions: balanced for any seqlen.
// Dot reduced over 32-lane clusters (5x shfl_xor); online softmax replicated.
// ---------------------------------------------------------------------------
__global__ __launch_bounds__(256, 8)
void attn_partial(const float* __restrict__ q,
                  const float* __restrict__ knew,
                  const float* __restrict__ vnew,
                  const float* __restrict__ kcache,
                  const float* __restrict__ vcache,
                  const int* __restrict__ seqlen,
                  float* __restrict__ ws)
{
    const int blk   = blockIdx.x;
    const int b     = blk & (B_ - 1);
    const int split = (blk >> 3) & (PSPLIT - 1);
    const int hg    = blk >> 10;
    const int t     = threadIdx.x;
    const int h     = hg * 8 + (t >> 5);
    const int dl    = t & 31;
    const int ds    = dl * 4;

    const int sl = seqlen[b];

    // q fragment: 4 floats
    const float4 qf = *(const float4*)(q + ((b * H_ + h) * D_ + ds));

    float m = -1e30f, l = 0.f;                 // -1e30 sentinel, NOT -inf
    float4 acc = make_float4(0.f, 0.f, 0.f, 0.f);

    const size_t poff  = (size_t)hg * 1024 + (size_t)t * 4;  // byte offset t*16 in position
    const float* kb = kcache + (size_t)b * SMAX_ * HD_ + poff;
    const float* vb = vcache + (size_t)b * SMAX_ * HD_ + poff;
    const size_t pstep = (size_t)HD_ * PSPLIT;

// one position from pointers KP/VP (4 floats, this thread's slice)
#define STEP1(KP, VP) do {                                                    \
    float4 k0 = *(const float4*)(KP);                                         \
    float4 v0 = *(const float4*)(VP);                                         \
    float s = qf.x*k0.x + qf.y*k0.y + qf.z*k0.z + qf.w*k0.w;                  \
    s += __shfl_xor(s, 1);  s += __shfl_xor(s, 2);  s += __shfl_xor(s, 4);    \
    s += __shfl_xor(s, 8);  s += __shfl_xor(s, 16);                           \
    s *= SCALE;                                                               \
    float mn = fmaxf(m, s);                                                   \
    float sc = __expf(m - mn);                                                \
    float pr = __expf(s - mn);                                                \
    m = mn; l = l * sc + pr;                                                  \
    acc.x = fmaf(pr, v0.x, acc.x * sc);                                       \
    acc.y = fmaf(pr, v0.y, acc.y * sc);                                       \
    acc.z = fmaf(pr, v0.z, acc.z * sc);                                       \
    acc.w = fmaf(pr, v0.w, acc.w * sc);                                       \
} while (0)

    int p = split;
    const float* kp = kb + (size_t)split * HD_;
    const float* vp = vb + (size_t)split * HD_;
    // unroll-2: two positions, 4 float4 loads in flight, two shfl chains overlap
    for (; p + PSPLIT < sl; p += 2 * PSPLIT) {
        float4 a0 = *(const float4*)(kp);
        float4 b0 = *(const float4*)(kp + pstep);
        float4 u0 = *(const float4*)(vp);
        float4 w0 = *(const float4*)(vp + pstep);

        float s0 = qf.x*a0.x + qf.y*a0.y + qf.z*a0.z + qf.w*a0.w;
        float s1 = qf.x*b0.x + qf.y*b0.y + qf.z*b0.z + qf.w*b0.w;
        s0 += __shfl_xor(s0, 1);  s0 += __shfl_xor(s0, 2);  s0 += __shfl_xor(s0, 4);
        s0 += __shfl_xor(s0, 8);  s0 += __shfl_xor(s0, 16);
        s1 += __shfl_xor(s1, 1);  s1 += __shfl_xor(s1, 2);  s1 += __shfl_xor(s1, 4);
        s1 += __shfl_xor(s1, 8);  s1 += __shfl_xor(s1, 16);
        s0 *= SCALE; s1 *= SCALE;

        float mn  = fmaxf(m, fmaxf(s0, s1));
        float sc  = __expf(m - mn);
        float pr0 = __expf(s0 - mn);
        float pr1 = __expf(s1 - mn);
        m = mn;
        l = l * sc + pr0 + pr1;
        acc.x = fmaf(pr1, w0.x, fmaf(pr0, u0.x, acc.x * sc));
        acc.y = fmaf(pr1, w0.y, fmaf(pr0, u0.y, acc.y * sc));
        acc.z = fmaf(pr1, w0.z, fmaf(pr0, u0.z, acc.z * sc));
        acc.w = fmaf(pr1, w0.w, fmaf(pr0, u0.w, acc.w * sc));
        kp += 2 * pstep;
        vp += 2 * pstep;
    }
    if (p < sl) {                              // leftover cache position
        STEP1(kp, vp);
    }
    // appended token at position sl (knew/vnew), owned by split sl % PSPLIT
    if ((sl & (PSPLIT - 1)) == split) {
        const float* kn = knew + (size_t)b * HD_ + poff;
        const float* vn = vnew + (size_t)b * HD_ + poff;
        STEP1(kn, vn);
    }
#undef STEP1

    // write partial record: {acc[128], m, l} per (b, split, h)
    float* wsp = ws + (((size_t)b * PSPLIT + split) * H_ + h) * PSTRIDE;
    *(float4*)(wsp + ds) = acc;                // 16B-aligned (528B records)
    if (dl == 0) { wsp[128] = m; wsp[129] = l; }
}

// ---------------------------------------------------------------------------
// Kernel 2: combine partials. grid = B*H blocks, 128 threads.
// Phase 1: threads strided over splits -> block max(m), lt = sum(l_s e_s).
// Phase 2: thread t = dim d -> a_d = sum_s e_s * acc[s][d] (coalesced 512B/s).
// ---------------------------------------------------------------------------
__global__ __launch_bounds__(128)
void attn_combine(const float* __restrict__ ws, float* __restrict__ out)
{
    const int bh = blockIdx.x;
    const int b  = bh >> 5;          // / H_
    const int h  = bh & (H_ - 1);
    const int t  = threadIdx.x;

    __shared__ float sm_e[PSPLIT];
    __shared__ float sm_w[2];

    const size_t sstride = (size_t)H_ * PSTRIDE;
    const float* base = ws + ((size_t)b * PSPLIT * H_ + h) * PSTRIDE;

    // phase 1a: max of m over splits
    float mx = -1e30f;
    for (int s = t; s < PSPLIT; s += 128) mx = fmaxf(mx, base[(size_t)s * sstride + 128]);
    #pragma unroll
    for (int off = 1; off < 64; off <<= 1) mx = fmaxf(mx, __shfl_xor(mx, off));
    if ((t & 63) == 0) sm_w[t >> 6] = mx;
    __syncthreads();
    const float mt = fmaxf(sm_w[0], sm_w[1]);
    __syncthreads();                                   // before sm_w reuse

    // phase 1b: per-split weights e_s and lt
    float le = 0.f;
    for (int s = t; s < PSPLIT; s += 128) {
        const float* p = base + (size_t)s * sstride;
        float ms = p[128], ls = p[129];
        float e = (ls > 0.f) ? __expf(ms - mt) : 0.f;  // empty split -> weight 0
        sm_e[s] = e;
        le += ls * e;
    }
    #pragma unroll
    for (int off = 1; off < 64; off <<= 1) le += __shfl_xor(le, off);
    if ((t & 63) == 0) sm_w[t >> 6] = le;
    __syncthreads();
    const float lt = sm_w[0] + sm_w[1];

    // phase 2: accumulate dimension t across splits
    const float* ab = base + t;
    float a = 0.f;
    #pragma unroll 8
    for (int s = 0; s < PSPLIT; ++s) {
        a += sm_e[s] * ab[(size_t)s * sstride];
    }
    out[bh * D_ + t] = a / lt;
}

extern "C" void kernel_launch(void* const* d_in, const int* in_sizes, int n_in,
                              void* d_out, int out_size, void* d_ws, size_t ws_size,
                              hipStream_t stream) {
    const float* q  = (const float*)d_in[0];
    const float* k  = (const float*)d_in[1];
    const float* v  = (const float*)d_in[2];
    const float* kc = (const float*)d_in[3];
    const float* vc = (const float*)d_in[4];
    const int*   sl = (const int*)d_in[5];
    float* out = (float*)d_out;
    float* ws  = (float*)d_ws;

    // 4096 fine-grained blocks (4 hgroups x 128 psplits x 8 batches), 2048
    // resident -> hardware dynamic dispatch balances CUs.
    // ws need: 8*128*32*132*4 = ~17 MB.
    attn_partial<<<NHG * PSPLIT * B_, 256, 0, stream>>>(q, k, v, kc, vc, sl, ws);
    attn_combine<<<B_ * H_, 128, 0, stream>>>(ws, out);
}